// Round 1
// baseline (44930.771 us; speedup 1.0000x reference)
//
#include <hip/hip_runtime.h>
#include <hip/hip_bf16.h>

#define SDIM 512
#define BDIM 64
#define INDIM 512
#define HDIM 1024
#define OUTDIM 512

typedef __bf16 bfreg;
typedef bfreg bf16x8 __attribute__((ext_vector_type(8)));
typedef bfreg bf16x4 __attribute__((ext_vector_type(4)));
typedef float f32x4 __attribute__((ext_vector_type(4)));

__device__ __forceinline__ float sigf(float x) { return 1.f / (1.f + __expf(-x)); }
__device__ __forceinline__ float tanhfast(float x) { return 1.f - 2.f / (__expf(2.f * x) + 1.f); }

// Convert fp32 -> bf16, concatenating two row-major sources along columns.
// dst: [nrows][ka+kb]; cols [0,ka) from sa, [ka,ka+kb) from sb. ka,kb % 4 == 0.
__global__ void concat_cvt(bfreg* __restrict__ dst,
                           const float* __restrict__ sa, int ka,
                           const float* __restrict__ sb, int kb, int nrows)
{
    const int k = ka + kb;
    const int k4 = k >> 2;
    const int total4 = nrows * k4;
    for (int i = blockIdx.x * blockDim.x + threadIdx.x; i < total4;
         i += gridDim.x * blockDim.x) {
        const int row = i / k4;
        const int cofs = (i - row * k4) * 4;
        const float* s = (cofs < ka) ? sa + (size_t)row * ka + cofs
                                     : sb + (size_t)row * kb + (cofs - ka);
        const float4 v = *(const float4*)s;
        bf16x4 o;
        o[0] = (bfreg)v.x; o[1] = (bfreg)v.y; o[2] = (bfreg)v.z; o[3] = (bfreg)v.w;
        *(bf16x4*)(dst + (size_t)row * k + cofs) = o;
    }
}

__global__ void bias_combine(float* __restrict__ b0, const float* __restrict__ bx0,
                             const float* __restrict__ bh0,
                             float* __restrict__ b1, const float* __restrict__ bx1,
                             const float* __restrict__ bh1)
{
    int i = blockIdx.x * blockDim.x + threadIdx.x;
    if (i < 4 * HDIM) {
        b0[i] = bx0[i] + bh0[i];
        b1[i] = bx1[i] + bh1[i];
    }
}

// One LSTM time step, input projection fused.
// gates[b, n] = sum_k A[b,k] * W[n,k] + bias[n], A = concat(src0_row, src1_row).
// W row-major [4*HDIM][K], K = K0 + HDIM. src0 rows: ld0. src1: [BDIM][HDIM] bf16.
// Grid: 256 blocks x 64 threads. Wave u owns h-units {4u..4u+3}, i.e. W rows
// {g*HDIM + 4u + uo : g in 0..3, uo in 0..3}. Each wave computes 64(batch) x 16 cols.
// mfma_f32_16x16x32_bf16 layouts: A row=lane&15, k=(lane>>4)*8+j (8 contig bf16);
// B col=lane&15, same k; C/D col=lane&15, row=(lane>>4)*4+reg.
__global__ void lstm_step(const bfreg* __restrict__ W, int K,
                          const float* __restrict__ bias,
                          const bfreg* __restrict__ src0, int ld0, int K0,
                          const bfreg* __restrict__ src1,
                          float* __restrict__ cst,
                          bfreg* __restrict__ hout)
{
    const int u = blockIdx.x;
    const int lane = threadIdx.x & 63;
    const int cl = lane & 15;
    const int kg = lane >> 4;
    const int gate = cl >> 2, uo = cl & 3;
    const int wr = gate * HDIM + u * 4 + uo;
    const bfreg* wp = W + (size_t)wr * K + kg * 8;

    f32x4 acc[4] = {};

    #pragma unroll 4
    for (int k0 = 0; k0 < K0; k0 += 32) {
        const bf16x8 b = *(const bf16x8*)(wp + k0);
        const bfreg* ap = src0 + k0 + kg * 8;
        #pragma unroll
        for (int m = 0; m < 4; ++m) {
            const bf16x8 a = *(const bf16x8*)(ap + (size_t)(m * 16 + cl) * ld0);
            acc[m] = __builtin_amdgcn_mfma_f32_16x16x32_bf16(a, b, acc[m], 0, 0, 0);
        }
    }
    const bfreg* wp1 = wp + K0;
    #pragma unroll 4
    for (int k0 = 0; k0 < HDIM; k0 += 32) {
        const bf16x8 b = *(const bf16x8*)(wp1 + k0);
        const bfreg* ap = src1 + k0 + kg * 8;
        #pragma unroll
        for (int m = 0; m < 4; ++m) {
            const bf16x8 a = *(const bf16x8*)(ap + (size_t)(m * 16 + cl) * HDIM);
            acc[m] = __builtin_amdgcn_mfma_f32_16x16x32_bf16(a, b, acc[m], 0, 0, 0);
        }
    }

    const float bl = bias[wr];
    const int lb = lane & 48;
    #pragma unroll
    for (int m = 0; m < 4; ++m) {
        #pragma unroll
        for (int r = 0; r < 4; ++r) {
            const float v = acc[m][r] + bl;
            // gather f,i,o,g for unit uo of this 16-lane group
            const float vf = __shfl(v, lb | uo, 64);
            const float vi = __shfl(v, lb | (uo + 4), 64);
            const float vo = __shfl(v, lb | (uo + 8), 64);
            const float vg = __shfl(v, lb | (uo + 12), 64);
            if (cl < 4) {
                const int j = u * 4 + cl;
                const int brow = m * 16 + kg * 4 + r;
                const float co = cst[brow * HDIM + j];
                const float fg = sigf(vf);
                const float ig = sigf(vi);
                const float og = sigf(vo);
                const float gg = tanhfast(vg);
                const float cn = fg * co + ig * gg;
                cst[brow * HDIM + j] = cn;
                hout[brow * HDIM + j] = (bfreg)(og * tanhfast(cn));
            }
        }
    }
}

// out[m, n] = sum_k A[m,k] * Wb[n,k] + bias[n]; A: [32768][HDIM], Wb: [OUTDIM][HDIM]
__global__ void fc_gemm(const bfreg* __restrict__ A, const bfreg* __restrict__ Wb,
                        const float* __restrict__ bias, float* __restrict__ out)
{
    const int lane = threadIdx.x & 63;
    const int wid = threadIdx.x >> 6;
    const int cl = lane & 15, kg = lane >> 4;
    const int mbase = blockIdx.y * 64 + (wid >> 1) * 32;
    const int nbase = blockIdx.x * 64 + (wid & 1) * 32;
    const bfreg* a0 = A + (size_t)(mbase + cl) * HDIM + kg * 8;
    const bfreg* a1 = a0 + (size_t)16 * HDIM;
    const bfreg* b0 = Wb + (size_t)(nbase + cl) * HDIM + kg * 8;
    const bfreg* b1 = b0 + (size_t)16 * HDIM;
    f32x4 acc[2][2] = {};
    #pragma unroll 4
    for (int k = 0; k < HDIM; k += 32) {
        const bf16x8 av0 = *(const bf16x8*)(a0 + k);
        const bf16x8 av1 = *(const bf16x8*)(a1 + k);
        const bf16x8 bv0 = *(const bf16x8*)(b0 + k);
        const bf16x8 bv1 = *(const bf16x8*)(b1 + k);
        acc[0][0] = __builtin_amdgcn_mfma_f32_16x16x32_bf16(av0, bv0, acc[0][0], 0, 0, 0);
        acc[0][1] = __builtin_amdgcn_mfma_f32_16x16x32_bf16(av0, bv1, acc[0][1], 0, 0, 0);
        acc[1][0] = __builtin_amdgcn_mfma_f32_16x16x32_bf16(av1, bv0, acc[1][0], 0, 0, 0);
        acc[1][1] = __builtin_amdgcn_mfma_f32_16x16x32_bf16(av1, bv1, acc[1][1], 0, 0, 0);
    }
    #pragma unroll
    for (int mi = 0; mi < 2; ++mi)
        #pragma unroll
        for (int ni = 0; ni < 2; ++ni)
            #pragma unroll
            for (int r = 0; r < 4; ++r) {
                const int row = mbase + mi * 16 + kg * 4 + r;
                const int col = nbase + ni * 16 + cl;
                out[(size_t)row * OUTDIM + col] = acc[mi][ni][r] + bias[col];
            }
}

extern "C" void kernel_launch(void* const* d_in, const int* in_sizes, int n_in,
                              void* d_out, int out_size, void* d_ws, size_t ws_size,
                              hipStream_t stream)
{
    const float* x     = (const float*)d_in[0];
    const float* l0_Wx = (const float*)d_in[1];
    const float* l0_Uh = (const float*)d_in[2];
    const float* l0_bx = (const float*)d_in[3];
    const float* l0_bh = (const float*)d_in[4];
    const float* l1_Wx = (const float*)d_in[5];
    const float* l1_Uh = (const float*)d_in[6];
    const float* l1_bx = (const float*)d_in[7];
    const float* l1_bh = (const float*)d_in[8];
    const float* fc_W  = (const float*)d_in[9];
    const float* fc_b  = (const float*)d_in[10];
    (void)in_sizes; (void)n_in; (void)out_size; (void)ws_size;

    char* p = (char*)d_ws;
    size_t off = 0;
    auto take = [&](size_t bytes) {
        void* r = p + off;
        off = (off + bytes + 255) & ~(size_t)255;
        return r;
    };

    bfreg* x_bf  = (bfreg*)take((size_t)SDIM * BDIM * INDIM * 2);
    bfreg* Wc0   = (bfreg*)take((size_t)4 * HDIM * (INDIM + HDIM) * 2);
    bfreg* Wc1   = (bfreg*)take((size_t)4 * HDIM * (2 * HDIM) * 2);
    bfreg* fcWb  = (bfreg*)take((size_t)OUTDIM * HDIM * 2);
    float* bias0 = (float*)take((size_t)4 * HDIM * 4);
    float* bias1 = (float*)take((size_t)4 * HDIM * 4);
    bfreg* Hb0   = (bfreg*)take((size_t)(SDIM + 1) * BDIM * HDIM * 2);
    bfreg* Hb1   = (bfreg*)take((size_t)(SDIM + 1) * BDIM * HDIM * 2);
    float* c0    = (float*)take((size_t)BDIM * HDIM * 4);
    float* c1    = (float*)take((size_t)BDIM * HDIM * 4);

    // zero initial h (slot 0 of Hb*) and cell states every call (determinism)
    hipMemsetAsync(Hb0, 0, (size_t)BDIM * HDIM * 2, stream);
    hipMemsetAsync(Hb1, 0, (size_t)BDIM * HDIM * 2, stream);
    hipMemsetAsync(c0, 0, (size_t)BDIM * HDIM * 4, stream);
    hipMemsetAsync(c1, 0, (size_t)BDIM * HDIM * 4, stream);

    // weight/input conversion to bf16 (+ per-layer col-concat [Wx | Uh])
    concat_cvt<<<2048, 256, 0, stream>>>(x_bf, x, SDIM * BDIM * INDIM, nullptr, 0, 1);
    concat_cvt<<<1024, 256, 0, stream>>>(Wc0, l0_Wx, INDIM, l0_Uh, HDIM, 4 * HDIM);
    concat_cvt<<<1024, 256, 0, stream>>>(Wc1, l1_Wx, HDIM, l1_Uh, HDIM, 4 * HDIM);
    concat_cvt<<<512, 256, 0, stream>>>(fcWb, fc_W, HDIM, nullptr, 0, OUTDIM);
    bias_combine<<<16, 256, 0, stream>>>(bias0, l0_bx, l0_bh, bias1, l1_bx, l1_bh);

    // layer 0 scan: step t reads h from Hb0 slot t, writes slot t+1
    for (int t = 0; t < SDIM; ++t)
        lstm_step<<<256, 64, 0, stream>>>(Wc0, INDIM + HDIM, bias0,
            x_bf + (size_t)t * BDIM * INDIM, INDIM, INDIM,
            Hb0 + (size_t)t * BDIM * HDIM, c0,
            Hb0 + (size_t)(t + 1) * BDIM * HDIM);

    // layer 1 scan: src0 = h0[t] (slot t+1 of Hb0), src1 = h1[t-1]
    for (int t = 0; t < SDIM; ++t)
        lstm_step<<<256, 64, 0, stream>>>(Wc1, 2 * HDIM, bias1,
            Hb0 + (size_t)(t + 1) * BDIM * HDIM, HDIM, HDIM,
            Hb1 + (size_t)t * BDIM * HDIM, c1,
            Hb1 + (size_t)(t + 1) * BDIM * HDIM);

    // FC head over all timesteps: A = Hb1 slots 1..SDIM
    fc_gemm<<<dim3(OUTDIM / 64, SDIM * BDIM / 64), 256, 0, stream>>>(
        Hb1 + (size_t)BDIM * HDIM, fcWb, fc_b, (float*)d_out);
}

// Round 2
// 13218.152 us; speedup vs baseline: 3.3992x; 3.3992x over previous
//
#include <hip/hip_runtime.h>
#include <hip/hip_bf16.h>

#define SDIM 512
#define BDIM 64
#define INDIM 512
#define HDIM 1024
#define OUTDIM 512
#define NWG 256
#define THREADS 512
#define BH (BDIM * HDIM)

typedef __bf16 bfreg;
typedef bfreg bf16x8 __attribute__((ext_vector_type(8)));
typedef bfreg bf16x4 __attribute__((ext_vector_type(4)));
typedef float f32x4 __attribute__((ext_vector_type(4)));

__device__ __forceinline__ float sigf(float x) { return 1.f / (1.f + __expf(-x)); }
__device__ __forceinline__ float tanhfast(float x) { return 1.f - 2.f / (__expf(2.f * x) + 1.f); }

// ---------- preamble kernels ----------

// fp32 -> bf16 flat convert (also used for fc weights / x)
__global__ void cvt_bf16(bfreg* __restrict__ dst, const float* __restrict__ src, int n4)
{
    for (int i = blockIdx.x * blockDim.x + threadIdx.x; i < n4; i += gridDim.x * blockDim.x) {
        const float4 v = *(const float4*)(src + (size_t)i * 4);
        bf16x4 o;
        o[0] = (bfreg)v.x; o[1] = (bfreg)v.y; o[2] = (bfreg)v.z; o[3] = (bfreg)v.w;
        *(bf16x4*)(dst + (size_t)i * 4) = o;
    }
}

__global__ void bias_combine(float* __restrict__ b0, const float* __restrict__ bx0,
                             const float* __restrict__ bh0,
                             float* __restrict__ b1, const float* __restrict__ bx1,
                             const float* __restrict__ bh1)
{
    int i = blockIdx.x * blockDim.x + threadIdx.x;
    if (i < 4 * HDIM) {
        b0[i] = bx0[i] + bh0[i];
        b1[i] = bx1[i] + bh1[i];
    }
}

// Pack W = [Wx | Uh] (row-major fp32) into per-WG MFMA B-fragment order, bf16.
// dst chunk idx = ((wg*2 + nt)*KST + ks)*64 + lane ; each chunk = 8 bf16.
// Within-WG gate-row rr = nt*16 + (lane&15); g = rr>>3, uo = rr&7;
// global row = g*HDIM + wg*8 + uo ; k = ks*32 + (lane>>4)*8 + j.
__global__ void pack_w(bfreg* __restrict__ dst, const float* __restrict__ Wx,
                       const float* __restrict__ Uh, int K0, int KH)
{
    const int KST = (K0 + KH) / 32;
    const int total = 128 * 2 * KST * 64;
    for (int idx = blockIdx.x * blockDim.x + threadIdx.x; idx < total;
         idx += gridDim.x * blockDim.x) {
        const int lane = idx & 63;
        int rem = idx >> 6;
        const int ks = rem % KST; rem /= KST;
        const int nt = rem & 1;
        const int wg = rem >> 1;
        const int rr = nt * 16 + (lane & 15);
        const int g = rr >> 3, uo = rr & 7;
        const int row = g * HDIM + wg * 8 + uo;
        const int k = ks * 32 + (lane >> 4) * 8;
        const float* s = (k < K0) ? Wx + (size_t)row * K0 + k
                                  : Uh + (size_t)row * KH + (k - K0);
        bfreg* d = dst + (size_t)idx * 8;
        #pragma unroll
        for (int j = 0; j < 8; ++j) d[j] = (bfreg)s[j];
    }
}

// ---------- grid barrier ----------

__device__ __forceinline__ void spin_until(unsigned* gen, unsigned target)
{
    while (__hip_atomic_load(gen, __ATOMIC_RELAXED, __HIP_MEMORY_SCOPE_AGENT) < target)
        __builtin_amdgcn_s_sleep(2);
}

// two-level barrier: 16 leaf counters (64B apart) -> master -> generation
__device__ __forceinline__ void grid_barrier(unsigned* bar, unsigned step)
{
    __syncthreads();
    if (threadIdx.x == 0) {
        __threadfence();   // release: drain + L2 writeback so h is LLC-visible
        unsigned* leaf = bar + (blockIdx.x & 15) * 16;
        unsigned* master = bar + 256;
        unsigned* gen = bar + 272;
        unsigned lv = __hip_atomic_fetch_add(leaf, 1u, __ATOMIC_ACQ_REL, __HIP_MEMORY_SCOPE_AGENT);
        if (lv == 15u) {
            __hip_atomic_store(leaf, 0u, __ATOMIC_RELAXED, __HIP_MEMORY_SCOPE_AGENT);
            unsigned mv = __hip_atomic_fetch_add(master, 1u, __ATOMIC_ACQ_REL, __HIP_MEMORY_SCOPE_AGENT);
            if (mv == 15u) {
                __hip_atomic_store(master, 0u, __ATOMIC_RELAXED, __HIP_MEMORY_SCOPE_AGENT);
                __hip_atomic_store(gen, step + 1u, __ATOMIC_RELEASE, __HIP_MEMORY_SCOPE_AGENT);
            } else {
                spin_until(gen, step + 1u);
            }
        } else {
            spin_until(gen, step + 1u);
        }
        __threadfence();   // acquire: invalidate L1/L2 before reading fresh h
    }
    __syncthreads();
}

// ---------- persistent 2-layer LSTM scan ----------
// grid = 256 WGs x 512 threads, 1 WG/CU (LDS-limited).
// WG: layer = wgid&1, row-group rg = wgid>>1 (owns h-units rg*8 .. rg*8+7,
// i.e. 32 gate rows ordered rr = g*8+uo). Waves: wid = (khalf<<2)|mtile.
// Pipelined: grid step s: layer0 computes h0[s] (s<512); layer1 computes
// h1[s-1] (s>=1). One grid barrier per step.
__global__ __launch_bounds__(THREADS, 2)
void lstm_scan(const bfreg* __restrict__ Pw0, const bfreg* __restrict__ Pw1,
               const float* __restrict__ bias0, const float* __restrict__ bias1,
               const bfreg* __restrict__ x_bf,
               bfreg* __restrict__ Hb0, bfreg* __restrict__ Hb1,
               unsigned* __restrict__ bar)
{
    extern __shared__ char smem[];
    const int wgid = blockIdx.x;
    const int layer = wgid & 1;
    const int rg = wgid >> 1;
    const int tid = threadIdx.x;
    const int l = tid & 63;
    const int wid = tid >> 6;
    const int m = wid & 3;          // m-tile (16 batch rows)
    const int kh = wid >> 2;        // K-half

    const int K0 = layer ? HDIM : INDIM;
    const int KST = layer ? (2 * HDIM) / 32 : (INDIM + HDIM) / 32;
    const size_t WELEM = (size_t)KST * 1024;      // bf16 elems of packed W per WG

    bfreg* lW = (bfreg*)smem;
    float* gatebuf = (float*)(smem + WELEM * 2);  // [2][32][68] f32
    float* cbuf = gatebuf + 2 * 32 * 68;          // [8][68] f32
    float* lbias = cbuf + 8 * 68;                 // [32]

    // stage packed weights (once)
    {
        const float4* wsrc = (const float4*)((layer ? Pw1 : Pw0) + (size_t)rg * WELEM);
        float4* wdst = (float4*)lW;
        const int n16 = KST * 128;                // 16B chunks
        for (int i = tid; i < n16; i += THREADS) wdst[i] = wsrc[i];
    }
    if (tid < 32) {
        const int g = tid >> 3, uo = tid & 7;
        lbias[tid] = (layer ? bias1 : bias0)[g * HDIM + rg * 8 + uo];
    }
    for (int i = tid; i < 8 * 68; i += THREADS) cbuf[i] = 0.f;
    __syncthreads();

    const int rowA = m * 16 + (l & 15);
    const int kofs = (l >> 4) * 8;
    const int ks_beg = kh * (KST / 2);
    const int ks_end = ks_beg + (KST / 2);

    for (unsigned s = 0; s <= SDIM; ++s) {
        const bool active = layer ? (s >= 1) : (s < SDIM);
        if (active) {
            const unsigned t = layer ? s - 1 : s;
            const bfreg* src0; int ld0;
            const bfreg* src1;
            bfreg* hdst;
            if (!layer) {
                src0 = x_bf + (size_t)t * BDIM * INDIM; ld0 = INDIM;
                src1 = Hb0 + (size_t)t * BH;            // h0[t-1]
                hdst = Hb0 + (size_t)(t + 1) * BH;
            } else {
                src0 = Hb0 + (size_t)(t + 1) * BH; ld0 = HDIM;   // h0[t]
                src1 = Hb1 + (size_t)t * BH;                     // h1[t-1]
                hdst = Hb1 + (size_t)(t + 1) * BH;
            }

            f32x4 acc0 = {0.f, 0.f, 0.f, 0.f};
            f32x4 acc1 = {0.f, 0.f, 0.f, 0.f};
            const bfreg* a0 = src0 + (size_t)rowA * ld0 + kofs;
            const bfreg* a1 = src1 + (size_t)rowA * HDIM + kofs;
            #pragma unroll 4
            for (int ks = ks_beg; ks < ks_end; ++ks) {
                const int k = ks * 32;
                const bfreg* ap = (k < K0) ? a0 + k : a1 + (k - K0);
                const bf16x8 a = *(const bf16x8*)ap;
                const bf16x8 w0 = *(const bf16x8*)(lW + ((size_t)ks * 64 + l) * 8);
                const bf16x8 w1 = *(const bf16x8*)(lW + ((size_t)(KST + ks) * 64 + l) * 8);
                acc0 = __builtin_amdgcn_mfma_f32_16x16x32_bf16(a, w0, acc0, 0, 0, 0);
                acc1 = __builtin_amdgcn_mfma_f32_16x16x32_bf16(a, w1, acc1, 0, 0, 0);
            }
            // C/D: col (=gate rr within ntile) = l&15 ; row (=batch) = m*16 + (l>>4)*4 + r
            float* gb = gatebuf + kh * (32 * 68);
            const int bb = m * 16 + (l >> 4) * 4;
            *(f32x4*)(gb + (0 * 16 + (l & 15)) * 68 + bb) = acc0;
            *(f32x4*)(gb + (1 * 16 + (l & 15)) * 68 + bb) = acc1;
            __syncthreads();

            // epilogue: thread -> (uo = tid&7, b = tid>>3)
            {
                const int uo = tid & 7, b = tid >> 3;
                float* g0 = gatebuf;
                float* g1 = gatebuf + 32 * 68;
                const float fv = g0[uo * 68 + b]        + g1[uo * 68 + b]        + lbias[uo];
                const float iv = g0[(8 + uo) * 68 + b]  + g1[(8 + uo) * 68 + b]  + lbias[8 + uo];
                const float ov = g0[(16 + uo) * 68 + b] + g1[(16 + uo) * 68 + b] + lbias[16 + uo];
                const float gv = g0[(24 + uo) * 68 + b] + g1[(24 + uo) * 68 + b] + lbias[24 + uo];
                const float c = cbuf[uo * 68 + b];
                const float fg = sigf(fv), ig = sigf(iv), og = sigf(ov);
                const float gg = tanhfast(gv);
                const float cn = fg * c + ig * gg;
                cbuf[uo * 68 + b] = cn;
                hdst[(size_t)b * HDIM + rg * 8 + uo] = (bfreg)(og * tanhfast(cn));
            }
        }
        grid_barrier(bar, s);
    }
}

// ---------- FC head ----------
__global__ void fc_gemm(const bfreg* __restrict__ A, const bfreg* __restrict__ Wb,
                        const float* __restrict__ bias, float* __restrict__ out)
{
    const int lane = threadIdx.x & 63;
    const int wid = threadIdx.x >> 6;
    const int cl = lane & 15, kg = lane >> 4;
    const int mbase = blockIdx.y * 64 + (wid >> 1) * 32;
    const int nbase = blockIdx.x * 64 + (wid & 1) * 32;
    const bfreg* a0 = A + (size_t)(mbase + cl) * HDIM + kg * 8;
    const bfreg* a1 = a0 + (size_t)16 * HDIM;
    const bfreg* b0 = Wb + (size_t)(nbase + cl) * HDIM + kg * 8;
    const bfreg* b1 = b0 + (size_t)16 * HDIM;
    f32x4 acc[2][2] = {};
    #pragma unroll 4
    for (int k = 0; k < HDIM; k += 32) {
        const bf16x8 av0 = *(const bf16x8*)(a0 + k);
        const bf16x8 av1 = *(const bf16x8*)(a1 + k);
        const bf16x8 bv0 = *(const bf16x8*)(b0 + k);
        const bf16x8 bv1 = *(const bf16x8*)(b1 + k);
        acc[0][0] = __builtin_amdgcn_mfma_f32_16x16x32_bf16(av0, bv0, acc[0][0], 0, 0, 0);
        acc[0][1] = __builtin_amdgcn_mfma_f32_16x16x32_bf16(av0, bv1, acc[0][1], 0, 0, 0);
        acc[1][0] = __builtin_amdgcn_mfma_f32_16x16x32_bf16(av1, bv0, acc[1][0], 0, 0, 0);
        acc[1][1] = __builtin_amdgcn_mfma_f32_16x16x32_bf16(av1, bv1, acc[1][1], 0, 0, 0);
    }
    #pragma unroll
    for (int mi = 0; mi < 2; ++mi)
        #pragma unroll
        for (int ni = 0; ni < 2; ++ni)
            #pragma unroll
            for (int r = 0; r < 4; ++r) {
                const int row = mbase + mi * 16 + kg * 4 + r;
                const int col = nbase + ni * 16 + cl;
                out[(size_t)row * OUTDIM + col] = acc[mi][ni][r] + bias[col];
            }
}

extern "C" void kernel_launch(void* const* d_in, const int* in_sizes, int n_in,
                              void* d_out, int out_size, void* d_ws, size_t ws_size,
                              hipStream_t stream)
{
    const float* x     = (const float*)d_in[0];
    const float* l0_Wx = (const float*)d_in[1];
    const float* l0_Uh = (const float*)d_in[2];
    const float* l0_bx = (const float*)d_in[3];
    const float* l0_bh = (const float*)d_in[4];
    const float* l1_Wx = (const float*)d_in[5];
    const float* l1_Uh = (const float*)d_in[6];
    const float* l1_bx = (const float*)d_in[7];
    const float* l1_bh = (const float*)d_in[8];
    const float* fc_W  = (const float*)d_in[9];
    const float* fc_b  = (const float*)d_in[10];
    (void)in_sizes; (void)n_in; (void)out_size; (void)ws_size;

    char* p = (char*)d_ws;
    size_t off = 0;
    auto take = [&](size_t bytes) {
        void* r = p + off;
        off = (off + bytes + 255) & ~(size_t)255;
        return r;
    };

    bfreg* x_bf  = (bfreg*)take((size_t)SDIM * BDIM * INDIM * 2);
    bfreg* Pw0   = (bfreg*)take((size_t)128 * 48 * 1024 * 2);   // 128 WG * KST48 * 1024 elems
    bfreg* Pw1   = (bfreg*)take((size_t)128 * 64 * 1024 * 2);
    bfreg* fcWb  = (bfreg*)take((size_t)OUTDIM * HDIM * 2);
    float* bias0 = (float*)take((size_t)4 * HDIM * 4);
    float* bias1 = (float*)take((size_t)4 * HDIM * 4);
    bfreg* Hb0   = (bfreg*)take((size_t)(SDIM + 1) * BH * 2);
    bfreg* Hb1   = (bfreg*)take((size_t)(SDIM + 1) * BH * 2);
    unsigned* bar = (unsigned*)take(4096);

    // deterministic init
    hipMemsetAsync(Hb0, 0, (size_t)BH * 2, stream);
    hipMemsetAsync(Hb1, 0, (size_t)BH * 2, stream);
    hipMemsetAsync(bar, 0, 4096, stream);

    cvt_bf16<<<2048, 256, 0, stream>>>(x_bf, x, SDIM * BDIM * INDIM / 4);
    cvt_bf16<<<512, 256, 0, stream>>>(fcWb, fc_W, OUTDIM * HDIM / 4);
    pack_w<<<3072, 256, 0, stream>>>(Pw0, l0_Wx, l0_Uh, INDIM, HDIM);
    pack_w<<<4096, 256, 0, stream>>>(Pw1, l1_Wx, l1_Uh, HDIM, HDIM);
    bias_combine<<<16, 256, 0, stream>>>(bias0, l0_bx, l0_bh, bias1, l1_bx, l1_bh);

    // LDS: packed W (max 128KB, layer1) + gatebuf 17408 + cbuf 2176 + bias 128
    const int smem_bytes = 64 * 2048 + 2 * 32 * 68 * 4 + 8 * 68 * 4 + 32 * 4;
    static bool attr_set = false;
    hipFuncSetAttribute((const void*)lstm_scan,
                        hipFuncAttributeMaxDynamicSharedMemorySize, smem_bytes);
    (void)attr_set;
    lstm_scan<<<NWG, THREADS, smem_bytes, stream>>>(Pw0, Pw1, bias0, bias1,
                                                    x_bf, Hb0, Hb1, bar);

    fc_gemm<<<dim3(OUTDIM / 64, SDIM * BDIM / 64), 256, 0, stream>>>(
        Hb1 + (size_t)BH, fcWb, fc_b, (float*)d_out);
}

// Round 3
// 9286.091 us; speedup vs baseline: 4.8385x; 1.4234x over previous
//
#include <hip/hip_runtime.h>
#include <hip/hip_bf16.h>

#define SDIM 512
#define BDIM 64
#define INDIM 512
#define HDIM 1024
#define OUTDIM 512
#define NWG 256
#define THREADS 512
#define BH (BDIM * HDIM)

typedef __bf16 bfreg;
typedef bfreg bf16x8 __attribute__((ext_vector_type(8)));
typedef bfreg bf16x4 __attribute__((ext_vector_type(4)));
typedef float f32x4 __attribute__((ext_vector_type(4)));

__device__ __forceinline__ float sigf(float x) { return 1.f / (1.f + __expf(-x)); }
__device__ __forceinline__ float tanhfast(float x) { return 1.f - 2.f / (__expf(2.f * x) + 1.f); }

// ---------- preamble kernels ----------

__global__ void cvt_bf16(bfreg* __restrict__ dst, const float* __restrict__ src, int n4)
{
    for (int i = blockIdx.x * blockDim.x + threadIdx.x; i < n4; i += gridDim.x * blockDim.x) {
        const float4 v = *(const float4*)(src + (size_t)i * 4);
        bf16x4 o;
        o[0] = (bfreg)v.x; o[1] = (bfreg)v.y; o[2] = (bfreg)v.z; o[3] = (bfreg)v.w;
        *(bf16x4*)(dst + (size_t)i * 4) = o;
    }
}

__global__ void bias_combine(float* __restrict__ b0, const float* __restrict__ bx0,
                             const float* __restrict__ bh0,
                             float* __restrict__ b1, const float* __restrict__ bx1,
                             const float* __restrict__ bh1)
{
    int i = blockIdx.x * blockDim.x + threadIdx.x;
    if (i < 4 * HDIM) {
        b0[i] = bx0[i] + bh0[i];
        b1[i] = bx1[i] + bh1[i];
    }
}

// Pack x [S][B][IN] fp32 -> chunked bf16 [S][IN/8][B][8]
__global__ void pack_x(bfreg* __restrict__ dst, const float* __restrict__ src)
{
    const int total = SDIM * (INDIM / 8) * BDIM;      // 16B chunks
    for (int idx = blockIdx.x * blockDim.x + threadIdx.x; idx < total;
         idx += gridDim.x * blockDim.x) {
        const int b = idx & (BDIM - 1);
        const int r = idx >> 6;
        const int kb = r & (INDIM / 8 - 1);
        const int t = r >> 6;
        const float* s = src + ((size_t)t * BDIM + b) * INDIM + kb * 8;
        bfreg* d = dst + (size_t)idx * 8;
        #pragma unroll
        for (int j = 0; j < 8; ++j) d[j] = (bfreg)s[j];
    }
}

// Pack W = [Wx | Uh] (row-major fp32) into per-WG MFMA B-fragment order, bf16.
// dst chunk idx = ((wg*2 + nt)*KST + ks)*64 + lane ; each chunk = 8 bf16.
// rr = nt*16 + (lane&15); g = rr>>3, uo = rr&7; row = g*HDIM + wg*8 + uo;
// k = ks*32 + (lane>>4)*8 + j.
__global__ void pack_w(bfreg* __restrict__ dst, const float* __restrict__ Wx,
                       const float* __restrict__ Uh, int K0, int KH)
{
    const int KST = (K0 + KH) / 32;
    const int total = 128 * 2 * KST * 64;
    for (int idx = blockIdx.x * blockDim.x + threadIdx.x; idx < total;
         idx += gridDim.x * blockDim.x) {
        const int lane = idx & 63;
        int rem = idx >> 6;
        const int ks = rem % KST; rem /= KST;
        const int nt = rem & 1;
        const int wg = rem >> 1;
        const int rr = nt * 16 + (lane & 15);
        const int g = rr >> 3, uo = rr & 7;
        const int row = g * HDIM + wg * 8 + uo;
        const int k = ks * 32 + (lane >> 4) * 8;
        const float* s = (k < K0) ? Wx + (size_t)row * K0 + k
                                  : Uh + (size_t)row * KH + (k - K0);
        bfreg* d = dst + (size_t)idx * 8;
        #pragma unroll
        for (int j = 0; j < 8; ++j) d[j] = (bfreg)s[j];
    }
}

// ---------- flag helpers ----------

__device__ __forceinline__ void wait_flags(const unsigned* f, int lane)
{
    const unsigned long long* p = (const unsigned long long*)f + lane;
    const unsigned long long EXP = 0x0000000100000001ull;
    while (true) {
        unsigned long long v = __hip_atomic_load(p, __ATOMIC_RELAXED, __HIP_MEMORY_SCOPE_AGENT);
        if (__all(v == EXP)) break;
        __builtin_amdgcn_s_sleep(1);
    }
}

// ---------- persistent 2-layer LSTM scan (flag-pipelined, no grid barrier) ----------
// 256 WGs x 512 threads, 1 WG/CU. layer = wgid&1, rg = wgid>>1 (8 h-units).
// Waves: wid = (kh<<2)|m. Each WG runs its own t loop; producer flags gate reads.
// h layout: [slot][u8(128)][b(64)][8] bf16 -> WG slice = 1KB contiguous; A-frag
// loads fully coalesced (chunk cb = ks*4+kg, addr = base + cb*512 + rowA*8).
__global__ __launch_bounds__(THREADS, 1)
void lstm_scan(const bfreg* __restrict__ Pw0, const bfreg* __restrict__ Pw1,
               const float* __restrict__ bias0, const float* __restrict__ bias1,
               const bfreg* __restrict__ x_pk,
               bfreg* __restrict__ Hb0, bfreg* __restrict__ Hb1,
               unsigned* __restrict__ flag0, unsigned* __restrict__ flag1)
{
    extern __shared__ char smem[];
    const int wgid = blockIdx.x;
    const int layer = wgid & 1;
    const int rg = wgid >> 1;
    const int tid = threadIdx.x;
    const int l = tid & 63;
    const int wid = tid >> 6;
    const int m = wid & 3;          // m-tile (16 batch rows)
    const int kh = wid >> 2;        // K-half

    const int KST = layer ? 64 : 48;
    const size_t WELEM = (size_t)KST * 1024;

    bfreg* lW = (bfreg*)smem;
    float* gatebuf = (float*)(smem + 64 * 2048);   // [2][32][68] f32 (fixed offset)
    float* cbuf = gatebuf + 2 * 32 * 68;           // [8][68]
    float* lbias = cbuf + 8 * 68;                  // [32]
    unsigned short* hbuf = (unsigned short*)(lbias + 32);  // [64][8] bf16

    // stage packed weights (once)
    {
        const float4* wsrc = (const float4*)((layer ? Pw1 : Pw0) + (size_t)rg * WELEM);
        float4* wdst = (float4*)lW;
        const int n16 = KST * 128;
        for (int i = tid; i < n16; i += THREADS) wdst[i] = wsrc[i];
    }
    if (tid < 32) {
        const int g = tid >> 3, uo = tid & 7;
        lbias[tid] = (layer ? bias1 : bias0)[g * HDIM + rg * 8 + uo];
    }
    for (int i = tid; i < 8 * 68; i += THREADS) cbuf[i] = 0.f;
    __syncthreads();

    const int cl = l & 15, kg = l >> 4;
    const int rowA = m * 16 + cl;
    const int ks_beg = kh * (KST / 2);
    const int ks_end = ks_beg + (KST / 2);
    const int KB0 = layer ? 128 : 64;              // chunks in src0

    unsigned* myflag = (layer ? flag1 : flag0) + rg;
    bfreg* Hme = layer ? Hb1 : Hb0;

    for (int t = 0; t < SDIM; ++t) {
        // ---- wait for producers (per-wave, only what this wave reads) ----
        if (!layer) {
            if (t > 0) wait_flags(flag0 + (size_t)(t - 1) * 128, l);
        } else {
            if (kh == 0) wait_flags(flag0 + (size_t)t * 128, l);          // needs h0[t]
            else if (t > 0) wait_flags(flag1 + (size_t)(t - 1) * 128, l); // needs h1[t-1]
        }
        asm volatile("" ::: "memory");

        const bfreg* s0 = layer ? Hb0 + (size_t)(t + 1) * BH
                                : x_pk + (size_t)t * (64 * BDIM * 8);
        const bfreg* s1 = layer ? Hb1 + (size_t)t * BH
                                : Hb0 + (size_t)t * BH;

        f32x4 acc0 = {0.f, 0.f, 0.f, 0.f};
        f32x4 acc1 = {0.f, 0.f, 0.f, 0.f};
        #pragma unroll 8
        for (int ks = ks_beg; ks < ks_end; ++ks) {
            const int cb = ks * 4 + kg;
            const bfreg* ap = (cb < KB0) ? s0 + (size_t)cb * 512 + rowA * 8
                                         : s1 + (size_t)(cb - KB0) * 512 + rowA * 8;
            const bf16x8 a = *(const bf16x8*)ap;
            const bf16x8 w0 = *(const bf16x8*)(lW + ((size_t)ks * 64 + l) * 8);
            const bf16x8 w1 = *(const bf16x8*)(lW + ((size_t)(KST + ks) * 64 + l) * 8);
            acc0 = __builtin_amdgcn_mfma_f32_16x16x32_bf16(a, w0, acc0, 0, 0, 0);
            acc1 = __builtin_amdgcn_mfma_f32_16x16x32_bf16(a, w1, acc1, 0, 0, 0);
        }
        // C/D: col(rr in ntile) = l&15 ; row(batch) = m*16 + (l>>4)*4 + r
        float* gb = gatebuf + kh * (32 * 68);
        const int bb = m * 16 + (l >> 4) * 4;
        *(f32x4*)(gb + (0 * 16 + cl) * 68 + bb) = acc0;
        *(f32x4*)(gb + (1 * 16 + cl) * 68 + bb) = acc1;
        __syncthreads();   // [A] gates ready

        // ---- epilogue: thread -> (uo = tid&7, b = tid>>3) ----
        {
            const int uo = tid & 7, b = tid >> 3;
            float* g0 = gatebuf;
            float* g1 = gatebuf + 32 * 68;
            const float fv = g0[uo * 68 + b]        + g1[uo * 68 + b]        + lbias[uo];
            const float iv = g0[(8 + uo) * 68 + b]  + g1[(8 + uo) * 68 + b]  + lbias[8 + uo];
            const float ov = g0[(16 + uo) * 68 + b] + g1[(16 + uo) * 68 + b] + lbias[16 + uo];
            const float gv = g0[(24 + uo) * 68 + b] + g1[(24 + uo) * 68 + b] + lbias[24 + uo];
            const float c = cbuf[uo * 68 + b];
            const float fg = sigf(fv), ig = sigf(iv), og = sigf(ov);
            const float gg = tanhfast(gv);
            const float cn = fg * c + ig * gg;
            cbuf[uo * 68 + b] = cn;
            const bfreg hv = (bfreg)(og * tanhfast(cn));
            hbuf[b * 8 + uo] = *(const unsigned short*)&hv;
        }
        __syncthreads();   // [B] hbuf ready

        // ---- publish h slice: write-through to LLC, then flag ----
        if (tid < 128) {
            const unsigned long long val = ((const unsigned long long*)hbuf)[tid];
            bfreg* dp = Hme + (size_t)(t + 1) * BH + rg * 512 + tid * 4;
            asm volatile("global_store_dwordx2 %0, %1, off sc0 sc1 nt"
                         :: "v"(dp), "v"(val) : "memory");
            asm volatile("s_waitcnt vmcnt(0)" ::: "memory");
        }
        __syncthreads();   // [C] slice globally visible
        if (tid == 0)
            __hip_atomic_store(myflag + (size_t)t * 128, 1u,
                               __ATOMIC_RELAXED, __HIP_MEMORY_SCOPE_AGENT);
    }
}

// ---------- FC head ----------
// A = Hb1 slots 1..512 in chunked layout; Wb row-major [OUT][HDIM]
__global__ void fc_gemm(const bfreg* __restrict__ Hb1, const bfreg* __restrict__ Wb,
                        const float* __restrict__ bias, float* __restrict__ out)
{
    const int lane = threadIdx.x & 63;
    const int wid = threadIdx.x >> 6;
    const int cl = lane & 15, kg = lane >> 4;
    const int mbase = blockIdx.y * 64 + (wid >> 1) * 32;
    const int nbase = blockIdx.x * 64 + (wid & 1) * 32;
    const int t = mbase >> 6;
    const int b0 = mbase & 63;
    const bfreg* pa0 = Hb1 + (size_t)(t + 1) * BH + (size_t)kg * 512 + (b0 + cl) * 8;
    const bfreg* pa1 = pa0 + 16 * 8;
    const bfreg* pb0 = Wb + (size_t)(nbase + cl) * HDIM + kg * 8;
    const bfreg* pb1 = pb0 + (size_t)16 * HDIM;
    f32x4 acc[2][2] = {};
    #pragma unroll 4
    for (int k = 0; k < HDIM; k += 32) {
        const size_t co = (size_t)(k >> 3) * 512;
        const bf16x8 av0 = *(const bf16x8*)(pa0 + co);
        const bf16x8 av1 = *(const bf16x8*)(pa1 + co);
        const bf16x8 bv0 = *(const bf16x8*)(pb0 + k);
        const bf16x8 bv1 = *(const bf16x8*)(pb1 + k);
        acc[0][0] = __builtin_amdgcn_mfma_f32_16x16x32_bf16(av0, bv0, acc[0][0], 0, 0, 0);
        acc[0][1] = __builtin_amdgcn_mfma_f32_16x16x32_bf16(av0, bv1, acc[0][1], 0, 0, 0);
        acc[1][0] = __builtin_amdgcn_mfma_f32_16x16x32_bf16(av1, bv0, acc[1][0], 0, 0, 0);
        acc[1][1] = __builtin_amdgcn_mfma_f32_16x16x32_bf16(av1, bv1, acc[1][1], 0, 0, 0);
    }
    #pragma unroll
    for (int mi = 0; mi < 2; ++mi)
        #pragma unroll
        for (int ni = 0; ni < 2; ++ni)
            #pragma unroll
            for (int r = 0; r < 4; ++r) {
                const int row = mbase + mi * 16 + kg * 4 + r;
                const int col = nbase + ni * 16 + cl;
                out[(size_t)row * OUTDIM + col] = acc[mi][ni][r] + bias[col];
            }
}

extern "C" void kernel_launch(void* const* d_in, const int* in_sizes, int n_in,
                              void* d_out, int out_size, void* d_ws, size_t ws_size,
                              hipStream_t stream)
{
    const float* x     = (const float*)d_in[0];
    const float* l0_Wx = (const float*)d_in[1];
    const float* l0_Uh = (const float*)d_in[2];
    const float* l0_bx = (const float*)d_in[3];
    const float* l0_bh = (const float*)d_in[4];
    const float* l1_Wx = (const float*)d_in[5];
    const float* l1_Uh = (const float*)d_in[6];
    const float* l1_bx = (const float*)d_in[7];
    const float* l1_bh = (const float*)d_in[8];
    const float* fc_W  = (const float*)d_in[9];
    const float* fc_b  = (const float*)d_in[10];
    (void)in_sizes; (void)n_in; (void)out_size; (void)ws_size;

    char* p = (char*)d_ws;
    size_t off = 0;
    auto take = [&](size_t bytes) {
        void* r = p + off;
        off = (off + bytes + 255) & ~(size_t)255;
        return r;
    };

    bfreg* x_pk  = (bfreg*)take((size_t)SDIM * BDIM * INDIM * 2);
    bfreg* Pw0   = (bfreg*)take((size_t)128 * 48 * 1024 * 2);
    bfreg* Pw1   = (bfreg*)take((size_t)128 * 64 * 1024 * 2);
    bfreg* fcWb  = (bfreg*)take((size_t)OUTDIM * HDIM * 2);
    float* bias0 = (float*)take((size_t)4 * HDIM * 4);
    float* bias1 = (float*)take((size_t)4 * HDIM * 4);
    bfreg* Hb0   = (bfreg*)take((size_t)(SDIM + 1) * BH * 2);
    bfreg* Hb1   = (bfreg*)take((size_t)(SDIM + 1) * BH * 2);
    unsigned* flag0 = (unsigned*)take((size_t)SDIM * 128 * 4);
    unsigned* flag1 = (unsigned*)take((size_t)SDIM * 128 * 4);

    // deterministic per-call init (graph-replayed)
    hipMemsetAsync(Hb0, 0, (size_t)BH * 2, stream);
    hipMemsetAsync(Hb1, 0, (size_t)BH * 2, stream);
    hipMemsetAsync(flag0, 0, (size_t)SDIM * 128 * 4, stream);
    hipMemsetAsync(flag1, 0, (size_t)SDIM * 128 * 4, stream);

    pack_x<<<4096, 256, 0, stream>>>(x_pk, x);
    cvt_bf16<<<512, 256, 0, stream>>>(fcWb, fc_W, OUTDIM * HDIM / 4);
    pack_w<<<3072, 256, 0, stream>>>(Pw0, l0_Wx, l0_Uh, INDIM, HDIM);
    pack_w<<<4096, 256, 0, stream>>>(Pw1, l1_Wx, l1_Uh, HDIM, HDIM);
    bias_combine<<<16, 256, 0, stream>>>(bias0, l0_bx, l0_bh, bias1, l1_bx, l1_bh);

    const int smem_bytes = 64 * 2048 + 2 * 32 * 68 * 4 + 8 * 68 * 4 + 32 * 4 + 64 * 8 * 2;
    hipFuncSetAttribute((const void*)lstm_scan,
                        hipFuncAttributeMaxDynamicSharedMemorySize, smem_bytes);
    lstm_scan<<<NWG, THREADS, smem_bytes, stream>>>(Pw0, Pw1, bias0, bias1,
                                                    x_pk, Hb0, Hb1, flag0, flag1);

    fc_gemm<<<dim3(OUTDIM / 64, SDIM * BDIM / 64), 256, 0, stream>>>(
        Hb1, fcWb, fc_b, (float*)d_out);
}

// Round 4
// 6185.703 us; speedup vs baseline: 7.2636x; 1.5012x over previous
//
#include <hip/hip_runtime.h>
#include <hip/hip_bf16.h>

#define SDIM 512
#define BDIM 64
#define INDIM 512
#define HDIM 1024
#define OUTDIM 512
#define NWG 256
#define THREADS 512
#define BH (BDIM * HDIM)

typedef __bf16 bfreg;
typedef bfreg bf16x8 __attribute__((ext_vector_type(8)));
typedef bfreg bf16x4 __attribute__((ext_vector_type(4)));
typedef float f32x4 __attribute__((ext_vector_type(4)));
typedef unsigned int u32x4 __attribute__((ext_vector_type(4)));

__device__ __forceinline__ float sigf(float x) { return 1.f / (1.f + __expf(-x)); }
__device__ __forceinline__ float tanhfast(float x) { return 1.f - 2.f / (__expf(2.f * x) + 1.f); }

// ---------- preamble kernels ----------

__global__ void cvt_bf16(bfreg* __restrict__ dst, const float* __restrict__ src, int n4)
{
    for (int i = blockIdx.x * blockDim.x + threadIdx.x; i < n4; i += gridDim.x * blockDim.x) {
        const float4 v = *(const float4*)(src + (size_t)i * 4);
        bf16x4 o;
        o[0] = (bfreg)v.x; o[1] = (bfreg)v.y; o[2] = (bfreg)v.z; o[3] = (bfreg)v.w;
        *(bf16x4*)(dst + (size_t)i * 4) = o;
    }
}

__global__ void bias_combine(float* __restrict__ b0, const float* __restrict__ bx0,
                             const float* __restrict__ bh0,
                             float* __restrict__ b1, const float* __restrict__ bx1,
                             const float* __restrict__ bh1)
{
    int i = blockIdx.x * blockDim.x + threadIdx.x;
    if (i < 4 * HDIM) {
        b0[i] = bx0[i] + bh0[i];
        b1[i] = bx1[i] + bh1[i];
    }
}

// Pack x [S][B][IN] fp32 -> chunked bf16 [S][IN/8][B][8]
__global__ void pack_x(bfreg* __restrict__ dst, const float* __restrict__ src)
{
    const int total = SDIM * (INDIM / 8) * BDIM;      // 16B chunks
    for (int idx = blockIdx.x * blockDim.x + threadIdx.x; idx < total;
         idx += gridDim.x * blockDim.x) {
        const int b = idx & (BDIM - 1);
        const int r = idx >> 6;
        const int kb = r & (INDIM / 8 - 1);
        const int t = r >> 6;
        const float* s = src + ((size_t)t * BDIM + b) * INDIM + kb * 8;
        bfreg* d = dst + (size_t)idx * 8;
        #pragma unroll
        for (int j = 0; j < 8; ++j) d[j] = (bfreg)s[j];
    }
}

// Pack W = [Wx | Uh] (row-major fp32) into per-WG MFMA B-fragment order, bf16.
// dst chunk idx = ((wg*2 + nt)*KST + ks)*64 + lane ; each chunk = 8 bf16.
// rr = nt*16 + (lane&15); g = rr>>3, uo = rr&7; row = g*HDIM + wg*8 + uo;
// k = ks*32 + (lane>>4)*8 + j.
__global__ void pack_w(bfreg* __restrict__ dst, const float* __restrict__ Wx,
                       const float* __restrict__ Uh, int K0, int KH)
{
    const int KST = (K0 + KH) / 32;
    const int total = 128 * 2 * KST * 64;
    for (int idx = blockIdx.x * blockDim.x + threadIdx.x; idx < total;
         idx += gridDim.x * blockDim.x) {
        const int lane = idx & 63;
        int rem = idx >> 6;
        const int ks = rem % KST; rem /= KST;
        const int nt = rem & 1;
        const int wg = rem >> 1;
        const int rr = nt * 16 + (lane & 15);
        const int g = rr >> 3, uo = rr & 7;
        const int row = g * HDIM + wg * 8 + uo;
        const int k = ks * 32 + (lane >> 4) * 8;
        const float* s = (k < K0) ? Wx + (size_t)row * K0 + k
                                  : Uh + (size_t)row * KH + (k - K0);
        bfreg* d = dst + (size_t)idx * 8;
        #pragma unroll
        for (int j = 0; j < 8; ++j) d[j] = (bfreg)s[j];
    }
}

// ---------- flag helpers ----------

__device__ __forceinline__ void wait_flags(const unsigned* f, int lane)
{
    const unsigned long long* p = (const unsigned long long*)f + lane;
    const unsigned long long EXP = 0x0000000100000001ull;
    while (true) {
        unsigned long long v = __hip_atomic_load(p, __ATOMIC_RELAXED, __HIP_MEMORY_SCOPE_AGENT);
        if (__all(v == EXP)) break;
        __builtin_amdgcn_s_sleep(1);
    }
}

__device__ __forceinline__ void lds_spin(int* r, int target)
{
    while (__hip_atomic_load(r, __ATOMIC_ACQUIRE, __HIP_MEMORY_SCOPE_WORKGROUP) < target)
        __builtin_amdgcn_s_sleep(1);
}

// ---------- persistent 2-layer LSTM scan (flag-pipelined, no grid barrier) ----------
// 256 WGs x 512 threads, 1 WG/CU. layer = wgid&1, rg = wgid>>1 (8 h-units).
// Waves: wid = (kh<<2)|m. ONE poller wave per cross-WG dependency; other waves
// spin on an LDS ready counter (no global traffic). Publish = wave 0 only:
// 1KB slice as 16B/lane sc0 sc1 (write-through to LLC, NO nt), vmcnt(0), then
// lane0 sets this WG's per-step flag.
__global__ __launch_bounds__(THREADS, 1)
void lstm_scan(const bfreg* __restrict__ Pw0, const bfreg* __restrict__ Pw1,
               const float* __restrict__ bias0, const float* __restrict__ bias1,
               const bfreg* __restrict__ x_pk,
               bfreg* __restrict__ Hb0, bfreg* __restrict__ Hb1,
               unsigned* __restrict__ flag0, unsigned* __restrict__ flag1)
{
    extern __shared__ char smem[];
    const int wgid = blockIdx.x;
    const int layer = wgid & 1;
    const int rg = wgid >> 1;
    const int tid = threadIdx.x;
    const int l = tid & 63;
    const int wid = tid >> 6;
    const int m = wid & 3;          // m-tile (16 batch rows)
    const int kh = wid >> 2;        // K-half

    const int KST = layer ? 64 : 48;
    const size_t WELEM = (size_t)KST * 1024;

    bfreg* lW = (bfreg*)smem;
    float* gatebuf = (float*)(smem + 64 * 2048);   // [2][32][68] f32 (fixed offset)
    float* cbuf = gatebuf + 2 * 32 * 68;           // [8][68]
    float* lbias = cbuf + 8 * 68;                  // [32]
    unsigned short* hbuf = (unsigned short*)(lbias + 32);  // [64][8] bf16
    int* ready = (int*)(hbuf + 64 * 8);            // [2] step counters

    // stage packed weights (once)
    {
        const float4* wsrc = (const float4*)((layer ? Pw1 : Pw0) + (size_t)rg * WELEM);
        float4* wdst = (float4*)lW;
        const int n16 = KST * 128;
        for (int i = tid; i < n16; i += THREADS) wdst[i] = wsrc[i];
    }
    if (tid < 32) {
        const int g = tid >> 3, uo = tid & 7;
        lbias[tid] = (layer ? bias1 : bias0)[g * HDIM + rg * 8 + uo];
    }
    if (tid < 2) ready[tid] = 0;
    for (int i = tid; i < 8 * 68; i += THREADS) cbuf[i] = 0.f;
    __syncthreads();

    const int cl = l & 15, kg = l >> 4;
    const int rowA = m * 16 + cl;
    const int ks_beg = kh * (KST / 2);
    const int ks_end = ks_beg + (KST / 2);
    const int KB0 = layer ? 128 : 64;              // chunks in src0

    unsigned* myflag = (layer ? flag1 : flag0) + rg;
    bfreg* Hme = layer ? Hb1 : Hb0;

    for (int t = 0; t < SDIM; ++t) {
        // ---- dependency wait: poller waves hit LLC, others spin on LDS ----
        if (!layer) {
            if (t > 0) {
                if (wid == 0) {
                    wait_flags(flag0 + (size_t)(t - 1) * 128, l);
                    __hip_atomic_store(&ready[0], t, __ATOMIC_RELEASE,
                                       __HIP_MEMORY_SCOPE_WORKGROUP);
                } else {
                    lds_spin(&ready[0], t);
                }
            }
        } else {
            if (wid == 0) {            // kh=0 group poller: needs h0[t]
                wait_flags(flag0 + (size_t)t * 128, l);
                __hip_atomic_store(&ready[0], t + 1, __ATOMIC_RELEASE,
                                   __HIP_MEMORY_SCOPE_WORKGROUP);
            } else if (wid == 4) {     // kh=1 group poller: needs h1[t-1]
                if (t > 0) {
                    wait_flags(flag1 + (size_t)(t - 1) * 128, l);
                    __hip_atomic_store(&ready[1], t, __ATOMIC_RELEASE,
                                       __HIP_MEMORY_SCOPE_WORKGROUP);
                }
            } else if (kh == 0) {
                lds_spin(&ready[0], t + 1);
            } else {
                if (t > 0) lds_spin(&ready[1], t);
            }
        }
        asm volatile("" ::: "memory");

        const bfreg* s0 = layer ? Hb0 + (size_t)(t + 1) * BH
                                : x_pk + (size_t)t * (64 * BDIM * 8);
        const bfreg* s1 = layer ? Hb1 + (size_t)t * BH
                                : Hb0 + (size_t)t * BH;

        f32x4 acc0 = {0.f, 0.f, 0.f, 0.f};
        f32x4 acc1 = {0.f, 0.f, 0.f, 0.f};
        #pragma unroll 8
        for (int ks = ks_beg; ks < ks_end; ++ks) {
            const int cb = ks * 4 + kg;
            const bfreg* ap = (cb < KB0) ? s0 + (size_t)cb * 512 + rowA * 8
                                         : s1 + (size_t)(cb - KB0) * 512 + rowA * 8;
            const bf16x8 a = *(const bf16x8*)ap;
            const bf16x8 w0 = *(const bf16x8*)(lW + ((size_t)ks * 64 + l) * 8);
            const bf16x8 w1 = *(const bf16x8*)(lW + ((size_t)(KST + ks) * 64 + l) * 8);
            acc0 = __builtin_amdgcn_mfma_f32_16x16x32_bf16(a, w0, acc0, 0, 0, 0);
            acc1 = __builtin_amdgcn_mfma_f32_16x16x32_bf16(a, w1, acc1, 0, 0, 0);
        }
        // C/D: col(rr in ntile) = l&15 ; row(batch) = m*16 + (l>>4)*4 + r
        float* gb = gatebuf + kh * (32 * 68);
        const int bb = m * 16 + (l >> 4) * 4;
        *(f32x4*)(gb + (0 * 16 + cl) * 68 + bb) = acc0;
        *(f32x4*)(gb + (1 * 16 + cl) * 68 + bb) = acc1;
        __syncthreads();   // [A] gates ready

        // ---- epilogue: thread -> (uo = tid&7, b = tid>>3) ----
        {
            const int uo = tid & 7, b = tid >> 3;
            float* g0 = gatebuf;
            float* g1 = gatebuf + 32 * 68;
            const float fv = g0[uo * 68 + b]        + g1[uo * 68 + b]        + lbias[uo];
            const float iv = g0[(8 + uo) * 68 + b]  + g1[(8 + uo) * 68 + b]  + lbias[8 + uo];
            const float ov = g0[(16 + uo) * 68 + b] + g1[(16 + uo) * 68 + b] + lbias[16 + uo];
            const float gv = g0[(24 + uo) * 68 + b] + g1[(24 + uo) * 68 + b] + lbias[24 + uo];
            const float c = cbuf[uo * 68 + b];
            const float fg = sigf(fv), ig = sigf(iv), og = sigf(ov);
            const float gg = tanhfast(gv);
            const float cn = fg * c + ig * gg;
            cbuf[uo * 68 + b] = cn;
            const bfreg hv = (bfreg)(og * tanhfast(cn));
            hbuf[b * 8 + uo] = *(const unsigned short*)&hv;
        }
        __syncthreads();   // [B] hbuf ready

        // ---- publish: wave 0 stores 1KB slice (16B/lane) + flag ----
        if (wid == 0) {
            const u32x4 val = ((const u32x4*)hbuf)[l];
            bfreg* dp = Hme + (size_t)(t + 1) * BH + rg * 512 + l * 8;
            asm volatile("global_store_dwordx4 %0, %1, off sc0 sc1"
                         :: "v"(dp), "v"(val) : "memory");
            asm volatile("s_waitcnt vmcnt(0)" ::: "memory");
            if (l == 0) {
                unsigned* fp = myflag + (size_t)t * 128;
                const unsigned one = 1u;
                asm volatile("global_store_dword %0, %1, off sc0 sc1"
                             :: "v"(fp), "v"(one) : "memory");
            }
        }
        // no WG-wide barrier here: gatebuf overwrite next iter is gated by [B];
        // waves only pass their next-step spin after this WG's own [B].
    }
}

// ---------- FC head ----------
// A = Hb1 slots 1..512 in chunked layout; Wb row-major [OUT][HDIM]
__global__ void fc_gemm(const bfreg* __restrict__ Hb1, const bfreg* __restrict__ Wb,
                        const float* __restrict__ bias, float* __restrict__ out)
{
    const int lane = threadIdx.x & 63;
    const int wid = threadIdx.x >> 6;
    const int cl = lane & 15, kg = lane >> 4;
    const int mbase = blockIdx.y * 64 + (wid >> 1) * 32;
    const int nbase = blockIdx.x * 64 + (wid & 1) * 32;
    const int t = mbase >> 6;
    const int b0 = mbase & 63;
    const bfreg* pa0 = Hb1 + (size_t)(t + 1) * BH + (size_t)kg * 512 + (b0 + cl) * 8;
    const bfreg* pa1 = pa0 + 16 * 8;
    const bfreg* pb0 = Wb + (size_t)(nbase + cl) * HDIM + kg * 8;
    const bfreg* pb1 = pb0 + (size_t)16 * HDIM;
    f32x4 acc[2][2] = {};
    #pragma unroll 4
    for (int k = 0; k < HDIM; k += 32) {
        const size_t co = (size_t)(k >> 3) * 512;
        const bf16x8 av0 = *(const bf16x8*)(pa0 + co);
        const bf16x8 av1 = *(const bf16x8*)(pa1 + co);
        const bf16x8 bv0 = *(const bf16x8*)(pb0 + k);
        const bf16x8 bv1 = *(const bf16x8*)(pb1 + k);
        acc[0][0] = __builtin_amdgcn_mfma_f32_16x16x32_bf16(av0, bv0, acc[0][0], 0, 0, 0);
        acc[0][1] = __builtin_amdgcn_mfma_f32_16x16x32_bf16(av0, bv1, acc[0][1], 0, 0, 0);
        acc[1][0] = __builtin_amdgcn_mfma_f32_16x16x32_bf16(av1, bv0, acc[1][0], 0, 0, 0);
        acc[1][1] = __builtin_amdgcn_mfma_f32_16x16x32_bf16(av1, bv1, acc[1][1], 0, 0, 0);
    }
    #pragma unroll
    for (int mi = 0; mi < 2; ++mi)
        #pragma unroll
        for (int ni = 0; ni < 2; ++ni)
            #pragma unroll
            for (int r = 0; r < 4; ++r) {
                const int row = mbase + mi * 16 + kg * 4 + r;
                const int col = nbase + ni * 16 + cl;
                out[(size_t)row * OUTDIM + col] = acc[mi][ni][r] + bias[col];
            }
}

extern "C" void kernel_launch(void* const* d_in, const int* in_sizes, int n_in,
                              void* d_out, int out_size, void* d_ws, size_t ws_size,
                              hipStream_t stream)
{
    const float* x     = (const float*)d_in[0];
    const float* l0_Wx = (const float*)d_in[1];
    const float* l0_Uh = (const float*)d_in[2];
    const float* l0_bx = (const float*)d_in[3];
    const float* l0_bh = (const float*)d_in[4];
    const float* l1_Wx = (const float*)d_in[5];
    const float* l1_Uh = (const float*)d_in[6];
    const float* l1_bx = (const float*)d_in[7];
    const float* l1_bh = (const float*)d_in[8];
    const float* fc_W  = (const float*)d_in[9];
    const float* fc_b  = (const float*)d_in[10];
    (void)in_sizes; (void)n_in; (void)out_size; (void)ws_size;

    char* p = (char*)d_ws;
    size_t off = 0;
    auto take = [&](size_t bytes) {
        void* r = p + off;
        off = (off + bytes + 255) & ~(size_t)255;
        return r;
    };

    bfreg* x_pk  = (bfreg*)take((size_t)SDIM * BDIM * INDIM * 2);
    bfreg* Pw0   = (bfreg*)take((size_t)128 * 48 * 1024 * 2);
    bfreg* Pw1   = (bfreg*)take((size_t)128 * 64 * 1024 * 2);
    bfreg* fcWb  = (bfreg*)take((size_t)OUTDIM * HDIM * 2);
    float* bias0 = (float*)take((size_t)4 * HDIM * 4);
    float* bias1 = (float*)take((size_t)4 * HDIM * 4);
    bfreg* Hb0   = (bfreg*)take((size_t)(SDIM + 1) * BH * 2);
    bfreg* Hb1   = (bfreg*)take((size_t)(SDIM + 1) * BH * 2);
    unsigned* flag0 = (unsigned*)take((size_t)SDIM * 128 * 4);
    unsigned* flag1 = (unsigned*)take((size_t)SDIM * 128 * 4);

    // deterministic per-call init (graph-replayed)
    hipMemsetAsync(Hb0, 0, (size_t)BH * 2, stream);
    hipMemsetAsync(Hb1, 0, (size_t)BH * 2, stream);
    hipMemsetAsync(flag0, 0, (size_t)SDIM * 128 * 4, stream);
    hipMemsetAsync(flag1, 0, (size_t)SDIM * 128 * 4, stream);

    pack_x<<<4096, 256, 0, stream>>>(x_pk, x);
    cvt_bf16<<<512, 256, 0, stream>>>(fcWb, fc_W, OUTDIM * HDIM / 4);
    pack_w<<<3072, 256, 0, stream>>>(Pw0, l0_Wx, l0_Uh, INDIM, HDIM);
    pack_w<<<4096, 256, 0, stream>>>(Pw1, l1_Wx, l1_Uh, HDIM, HDIM);
    bias_combine<<<16, 256, 0, stream>>>(bias0, l0_bx, l0_bh, bias1, l1_bx, l1_bh);

    const int smem_bytes = 64 * 2048 + 2 * 32 * 68 * 4 + 8 * 68 * 4 + 32 * 4
                         + 64 * 8 * 2 + 16;
    hipFuncSetAttribute((const void*)lstm_scan,
                        hipFuncAttributeMaxDynamicSharedMemorySize, smem_bytes);
    lstm_scan<<<NWG, THREADS, smem_bytes, stream>>>(Pw0, Pw1, bias0, bias1,
                                                    x_pk, Hb0, Hb1, flag0, flag1);

    fc_gemm<<<dim3(OUTDIM / 64, SDIM * BDIM / 64), 256, 0, stream>>>(
        Hb1, fcWb, fc_b, (float*)d_out);
}